// Round 13
// baseline (360.540 us; speedup 1.0000x reference)
//
#include <hip/hip_runtime.h>
#include <hip/hip_bf16.h>

#define DIM 128
#define LDS_STRIDE 136  // bf16 stage stride (272B rows)
#define SC_STRIDE 132   // f32 epilogue stride

typedef __attribute__((ext_vector_type(8))) __bf16 bf16x8;
typedef __attribute__((ext_vector_type(4))) __bf16 bf16x4;
typedef __attribute__((ext_vector_type(4))) float f32x4;

// ---------------------------------------------------------------------------
// Wt layout: [0..3]=Wd0..3, [4..6]=Wa0..2, [7]=Wh0, [8]=Wh1, [9]=Wh2
// ---------------------------------------------------------------------------

// ---------------------------------------------------------------------------
// count_prep: fused independent prologue.
//   blocks [0, GE)            : CSR count (scatter atomics, latency-bound)
//   blocks [GE, GE+HB)        : h (f32) -> bf16 into d_out        (BW-bound)
//   blocks [GE+HB, GE+HB+WB)  : transpose 10 W blocks -> Wt       (tiny)
// ---------------------------------------------------------------------------
__global__ __launch_bounds__(256) void count_prep(const int* __restrict__ a_idx,
                                                  const int* __restrict__ d_idx,
                                                  int* __restrict__ offs,
                                                  const float* __restrict__ h,
                                                  __bf16* __restrict__ hb,
                                                  const float* __restrict__ W_a,
                                                  const float* __restrict__ W_d,
                                                  const float* __restrict__ W_h,
                                                  __bf16* __restrict__ Wt,
                                                  int EA, int ED, int N,
                                                  int GE, int HB)
{
    const int b = blockIdx.x;
    const int tid = threadIdx.x;
    if (b < GE) {
        int e = b * 256 + tid;
        if (e < EA) {
            atomicAdd(&offs[a_idx[3 * (size_t)e + 1]], 1);
        } else if (e < EA + ED) {
            int k = e - EA;
            atomicAdd(&offs[N + d_idx[4 * (size_t)k + 1]], 1);
        }
        return;
    }
    if (b < GE + HB) {
        int i = ((b - GE) * 256 + tid) * 8;
        if (i >= N * DIM) return;
        float4 v0 = *(const float4*)(h + i);
        float4 v1 = *(const float4*)(h + i + 4);
        bf16x8 o;
        o[0] = (__bf16)v0.x; o[1] = (__bf16)v0.y; o[2] = (__bf16)v0.z; o[3] = (__bf16)v0.w;
        o[4] = (__bf16)v1.x; o[5] = (__bf16)v1.y; o[6] = (__bf16)v1.z; o[7] = (__bf16)v1.w;
        *(bf16x8*)(hb + i) = o;
        return;
    }
    {
        int idx = (b - GE - HB) * 256 + tid;
        if (idx >= 10 * 16384) return;
        int t   = idx >> 14;
        int rem = idx & 16383;
        int c   = rem >> 7;
        int k   = rem & 127;
        const float* src;
        if (t < 4)      src = W_d + (size_t)t * 16384;
        else if (t < 7) src = W_a + (size_t)(t - 4) * 16384;
        else            src = W_h + (size_t)(t - 7) * 16384;
        Wt[(size_t)t * 16384 + c * 128 + k] = (__bf16)src[k * 128 + c];
    }
}

__device__ __forceinline__ void stage_wt(const __bf16* __restrict__ Wtj,
                                         __bf16 (*sB)[LDS_STRIDE], int tid)
{
    for (int it = 0; it < 8; ++it) {
        int idx = tid + it * 256;
        int c  = idx >> 4;
        int k8 = (idx & 15) << 3;
        *(bf16x8*)&sB[c][k8] = *(const bf16x8*)(Wtj + c * 128 + k8);
    }
}

__device__ __forceinline__ void load_afrag_f32(const float* __restrict__ src,
                                               int row, int lk, int N, bf16x8 afrag[4])
{
    const float* rp = src + (size_t)row * DIM;
    #pragma unroll
    for (int ks = 0; ks < 4; ++ks) {
        float4 v0 = make_float4(0.f, 0.f, 0.f, 0.f), v1 = v0;
        if (row < N) {
            v0 = *(const float4*)(rp + ks * 32 + lk);
            v1 = *(const float4*)(rp + ks * 32 + lk + 4);
        }
        bf16x8 a;
        a[0] = (__bf16)v0.x; a[1] = (__bf16)v0.y; a[2] = (__bf16)v0.z; a[3] = (__bf16)v0.w;
        a[4] = (__bf16)v1.x; a[5] = (__bf16)v1.y; a[6] = (__bf16)v1.z; a[7] = (__bf16)v1.w;
        afrag[ks] = a;
    }
}

__device__ __forceinline__ void load_afrag_bf16(const __bf16* __restrict__ src,
                                                int row, int lk, int N, bf16x8 afrag[4])
{
    const __bf16* rp = src + (size_t)row * DIM;
    #pragma unroll
    for (int ks = 0; ks < 4; ++ks) {
        bf16x8 a = {};
        if (row < N) a = *(const bf16x8*)(rp + ks * 32 + lk);
        afrag[ks] = a;
    }
}

// shared proj body: one (64-row tile, j) pair; bf16 A-loads; LDS epilogue
__device__ __forceinline__ void proj_body(const __bf16* __restrict__ src,
                                          const __bf16* __restrict__ Wtj,
                                          __bf16* __restrict__ dj,
                                          __bf16 (*sB)[LDS_STRIDE],
                                          int node0, int tid, int N)
{
    float* sC = reinterpret_cast<float*>(sB);
    const int wave = tid >> 6, lane = tid & 63;
    const int lrow = lane & 15;
    const int lk   = (lane >> 4) * 8;
    const int arow = node0 + wave * 16 + lrow;

    stage_wt(Wtj, sB, tid);
    bf16x8 afrag[4];
    load_afrag_bf16(src, arow, lk, N, afrag);
    __syncthreads();

    f32x4 acc[8];
    #pragma unroll
    for (int ct = 0; ct < 8; ++ct) acc[ct] = (f32x4){0.f, 0.f, 0.f, 0.f};

    #pragma unroll
    for (int ks = 0; ks < 4; ++ks) {
        int k0 = ks * 32 + lk;
        #pragma unroll
        for (int ct = 0; ct < 8; ++ct) {
            bf16x8 b = *(const bf16x8*)&sB[ct * 16 + lrow][k0];
            acc[ct] = __builtin_amdgcn_mfma_f32_16x16x32_bf16(afrag[ks], b, acc[ct], 0, 0, 0);
        }
    }

    __syncthreads();
    {
        int rbase = wave * 16 + (lane >> 4) * 4;
        #pragma unroll
        for (int r = 0; r < 4; ++r)
            #pragma unroll
            for (int ct = 0; ct < 8; ++ct)
                sC[(rbase + r) * SC_STRIDE + ct * 16 + lrow] = acc[ct][r];
    }
    __syncthreads();

    for (int it = 0; it < 8; ++it) {
        int idx = tid + it * 256;
        int row = idx >> 5;
        int c4  = (idx & 31) << 2;
        int grow = node0 + row;
        if (grow < N) {
            const float* sp = sC + row * SC_STRIDE + c4;
            bf16x4 o;
            o[0] = (__bf16)sp[0]; o[1] = (__bf16)sp[1];
            o[2] = (__bf16)sp[2]; o[3] = (__bf16)sp[3];
            *(bf16x4*)(dj + (size_t)grow * DIM + c4) = o;
        }
    }
}

// ---------------------------------------------------------------------------
// fill_projD: fused. blocks [0, FILLB) = CSR fill (latency-bound scatter);
// blocks [FILLB, +4*NT64) = dihedral proj (MFMA-bound). Complementary pipes.
// Fill-first grid order: long latency chains start immediately.
// ---------------------------------------------------------------------------
__global__ __launch_bounds__(256, 4) void fill_projD(const int* __restrict__ a_idx,
                                                     const float* __restrict__ a_val,
                                                     const int* __restrict__ d_idx,
                                                     const float* __restrict__ d_val,
                                                     int* __restrict__ offs,
                                                     int4* __restrict__ recs,
                                                     const __bf16* __restrict__ hb,
                                                     const __bf16* __restrict__ Wt,
                                                     __bf16* __restrict__ P,
                                                     int EA, int ED, int N, int FILLB)
{
    __shared__ __bf16 sB[128][LDS_STRIDE];
    const int tid = threadIdx.x;
    if ((int)blockIdx.x < FILLB) {
        int e = blockIdx.x * 256 + tid;
        if (e < EA) {
            int i0 = a_idx[3 * (size_t)e + 0];
            int i1 = a_idx[3 * (size_t)e + 1];
            int i2 = a_idx[3 * (size_t)e + 2];
            int slot = atomicAdd(&offs[i1], 1);
            recs[slot] = make_int4(i0 * 256, i2 * 256, __float_as_int(a_val[e]), 0);
        } else if (e < EA + ED) {
            int k = e - EA;
            int i0 = d_idx[4 * (size_t)k + 0];
            int i1 = d_idx[4 * (size_t)k + 1];
            int i2 = d_idx[4 * (size_t)k + 2];
            int i3 = d_idx[4 * (size_t)k + 3];
            int slot = atomicAdd(&offs[N + i1], 1);
            recs[slot] = make_int4(i0 * 256, i2 * 256, i3 * 256, __float_as_int(d_val[k]));
        }
        return;
    }
    int pb = blockIdx.x - FILLB;
    int tile = pb >> 2, j = pb & 3;   // consecutive blocks share h tile (L2)
    proj_body(hb, Wt + (size_t)j * 16384, P + (size_t)j * N * DIM,
              sB, tile * 64, tid, N);
}

// standalone proj for the angle pass (Wt slots 4..7 -> P[0..2]=Wa, P[3]=Wh0)
__global__ __launch_bounds__(256, 4) void proj(const __bf16* __restrict__ src,
                                               const __bf16* __restrict__ Wt,
                                               __bf16* __restrict__ dst,
                                               int N)
{
    __shared__ __bf16 sB[128][LDS_STRIDE];
    const int pb = blockIdx.x;
    const int tile = pb >> 2, j = pb & 3;
    proj_body(src, Wt + (size_t)j * 16384, dst + (size_t)j * N * DIM,
              sB, tile * 64, threadIdx.x, N);
}

#define SCAN_CHUNK 1024

__global__ __launch_bounds__(256) void scan_s1(int* __restrict__ data,
                                               int* __restrict__ partials, int n)
{
    __shared__ int lds[256];
    const int t = threadIdx.x;
    const int base = blockIdx.x * SCAN_CHUNK + t * 4;
    int v[4];
    #pragma unroll
    for (int i = 0; i < 4; ++i) v[i] = (base + i < n) ? data[base + i] : 0;
    int tsum = v[0] + v[1] + v[2] + v[3];
    lds[t] = tsum; __syncthreads();
    for (int off = 1; off < 256; off <<= 1) {
        int x = (t >= off) ? lds[t - off] : 0;
        __syncthreads();
        lds[t] += x;
        __syncthreads();
    }
    if (t == 255) partials[blockIdx.x] = lds[255];
    int run = lds[t] - tsum;
    #pragma unroll
    for (int i = 0; i < 4; ++i) {
        int nv = run; run += v[i];
        if (base + i < n) data[base + i] = nv;
    }
}

__global__ __launch_bounds__(256) void scan_s2(int* __restrict__ partials, int nb)
{
    __shared__ int lds[256];
    const int t = threadIdx.x;
    int v = (t < nb) ? partials[t] : 0;
    lds[t] = v; __syncthreads();
    for (int off = 1; off < 256; off <<= 1) {
        int x = (t >= off) ? lds[t - off] : 0;
        __syncthreads();
        lds[t] += x;
        __syncthreads();
    }
    if (t < nb) partials[t] = lds[t] - v;
}

__global__ __launch_bounds__(256) void scan_s3(int* __restrict__ data,
                                               const int* __restrict__ partials, int n)
{
    const int add = partials[blockIdx.x];
    const int base = blockIdx.x * SCAN_CHUNK + threadIdx.x * 4;
    #pragma unroll
    for (int i = 0; i < 4; ++i)
        if (base + i < n) data[base + i] += add;
}

__device__ __forceinline__ float silu(float x) { return x / (1.f + __expf(-x)); }

// ---------------------------------------------------------------------------
// gather3: half-wave-per-edge (proven). agg_a f32 -> d_out.
// ---------------------------------------------------------------------------
__global__ __launch_bounds__(256) void gather3(const __bf16* __restrict__ P,
                                               const float* __restrict__ wlast,
                                               const float* __restrict__ bias,
                                               const int* __restrict__ offs,
                                               const int4* __restrict__ recs,
                                               float* __restrict__ aggf, int N)
{
    const int tid = threadIdx.x;
    const int n = blockIdx.x * 4 + (tid >> 6);
    if (n >= N) return;
    const int lane = tid & 63;
    const int half = lane >> 5;
    const int gl = lane & 31;
    const int f  = gl * 4;
    const int fb = gl * 8;
    const size_t NBb = (size_t)N * DIM * 2;
    const char* P0b = (const char*)P;
    const char* P1b = P0b + NBb;
    const char* P2b = P0b + 2 * NBb;
    int start = (n == 0) ? 0 : offs[n - 1];
    int end = offs[n];

    float wl[4], base[4];
    {
        const float* wp = wlast + f;
        const float* bp = bias + f;
        bf16x4 p1 = *(const bf16x4*)(P1b + (size_t)n * 256 + fb);
        #pragma unroll
        for (int c = 0; c < 4; ++c) { wl[c] = wp[c]; base[c] = (float)p1[c] + bp[c]; }
    }
    float a[4] = {0.f, 0.f, 0.f, 0.f};

    const int cnt = end - start;
    const int npair = cnt >> 1;
    int s = start;
    for (int p = 0; p < npair; ++p, s += 2) {
        int4 r = recs[s + half];
        bf16x4 q0 = *(const bf16x4*)(P0b + r.x + fb);
        bf16x4 q2 = *(const bf16x4*)(P2b + r.y + fb);
        float v = __int_as_float(r.z);
        #pragma unroll
        for (int c = 0; c < 4; ++c)
            a[c] += silu((float)q0[c] + (float)q2[c] + v * wl[c] + base[c]);
    }
    if (cnt & 1) {
        int4 r = recs[end - 1];
        bf16x4 q0 = *(const bf16x4*)(P0b + r.x + fb);
        bf16x4 q2 = *(const bf16x4*)(P2b + r.y + fb);
        float v = __int_as_float(r.z);
        if (half == 0) {
            #pragma unroll
            for (int c = 0; c < 4; ++c)
                a[c] += silu((float)q0[c] + (float)q2[c] + v * wl[c] + base[c]);
        }
    }
    #pragma unroll
    for (int c = 0; c < 4; ++c) a[c] += __shfl_xor(a[c], 32, 64);
    if (half == 0) {
        f32x4 o;
        #pragma unroll
        for (int c = 0; c < 4; ++c) o[c] = a[c];
        *(f32x4*)(aggf + (size_t)n * DIM + f) = o;
    }
}

__global__ __launch_bounds__(256) void gather4(const __bf16* __restrict__ P,
                                               const float* __restrict__ wlast,
                                               const float* __restrict__ bias,
                                               const int* __restrict__ offs_d,
                                               const int4* __restrict__ recs,
                                               __bf16* __restrict__ agg, int N)
{
    const int tid = threadIdx.x;
    const int n = blockIdx.x * 4 + (tid >> 6);
    if (n >= N) return;
    const int lane = tid & 63;
    const int half = lane >> 5;
    const int gl = lane & 31;
    const int f  = gl * 4;
    const int fb = gl * 8;
    const size_t NBb = (size_t)N * DIM * 2;
    const char* P0b = (const char*)P;
    const char* P1b = P0b + NBb;
    const char* P2b = P0b + 2 * NBb;
    const char* P3b = P0b + 3 * NBb;
    int start = offs_d[n - 1];  // n==0 -> offs[N-1] == EA == dihedral base
    int end = offs_d[n];

    float wl[4], base[4];
    {
        const float* wp = wlast + f;
        const float* bp = bias + f;
        bf16x4 p1 = *(const bf16x4*)(P1b + (size_t)n * 256 + fb);
        #pragma unroll
        for (int c = 0; c < 4; ++c) { wl[c] = wp[c]; base[c] = (float)p1[c] + bp[c]; }
    }
    float a[4] = {0.f, 0.f, 0.f, 0.f};

    const int cnt = end - start;
    const int npair = cnt >> 1;
    int s = start;
    for (int p = 0; p < npair; ++p, s += 2) {
        int4 r = recs[s + half];
        bf16x4 q0 = *(const bf16x4*)(P0b + r.x + fb);
        bf16x4 q2 = *(const bf16x4*)(P2b + r.y + fb);
        bf16x4 q3 = *(const bf16x4*)(P3b + r.z + fb);
        float v = __int_as_float(r.w);
        #pragma unroll
        for (int c = 0; c < 4; ++c)
            a[c] += silu((float)q0[c] + (float)q2[c] + (float)q3[c] + v * wl[c] + base[c]);
    }
    if (cnt & 1) {
        int4 r = recs[end - 1];
        bf16x4 q0 = *(const bf16x4*)(P0b + r.x + fb);
        bf16x4 q2 = *(const bf16x4*)(P2b + r.y + fb);
        bf16x4 q3 = *(const bf16x4*)(P3b + r.z + fb);
        float v = __int_as_float(r.w);
        if (half == 0) {
            #pragma unroll
            for (int c = 0; c < 4; ++c)
                a[c] += silu((float)q0[c] + (float)q2[c] + (float)q3[c] + v * wl[c] + base[c]);
        }
    }
    #pragma unroll
    for (int c = 0; c < 4; ++c) a[c] += __shfl_xor(a[c], 32, 64);
    if (half == 0) {
        bf16x4 o;
        #pragma unroll
        for (int c = 0; c < 4; ++c) o[c] = (__bf16)a[c];
        *(bf16x4*)(agg + (size_t)n * DIM + f) = o;
    }
}

// ---------------------------------------------------------------------------
// update2: out = h + bh + PH + aggA@Wt[0] + aggD@Wt[1]   (2 MFMA stages)
// PH = h@Wh0 from the angle proj pass (P[3]). aggA lives IN d_out.
// ---------------------------------------------------------------------------
__global__ __launch_bounds__(256, 4) void update2(const float* __restrict__ h,
                                                  const float* __restrict__ aggA,
                                                  const __bf16* __restrict__ aggD,
                                                  const __bf16* __restrict__ PH,
                                                  const __bf16* __restrict__ Wt,
                                                  const float* __restrict__ bh,
                                                  float* __restrict__ out, int N)
{
    __shared__ __bf16 sB[128][LDS_STRIDE];
    float* sC = reinterpret_cast<float*>(sB);
    const int tid = threadIdx.x;
    const int node0 = blockIdx.x * 64;
    const int wave = tid >> 6, lane = tid & 63;
    const int lrow = lane & 15;
    const int lk   = (lane >> 4) * 8;
    const int arow = node0 + wave * 16 + lrow;

    bf16x8 aA[4], aD[4];
    load_afrag_f32(aggA, arow, lk, N, aA);
    load_afrag_bf16(aggD, arow, lk, N, aD);

    f32x4 acc[8];
    #pragma unroll
    for (int ct = 0; ct < 8; ++ct) acc[ct] = (f32x4){0.f, 0.f, 0.f, 0.f};

    #pragma unroll
    for (int s = 0; s < 2; ++s) {
        __syncthreads();
        stage_wt(Wt + (size_t)s * 16384, sB, tid);
        __syncthreads();

        #pragma unroll
        for (int ks = 0; ks < 4; ++ks) {
            int k0 = ks * 32 + lk;
            #pragma unroll
            for (int ct = 0; ct < 8; ++ct) {
                bf16x8 b = *(const bf16x8*)&sB[ct * 16 + lrow][k0];
                bf16x8 af = (s == 0) ? aA[ks] : aD[ks];
                acc[ct] = __builtin_amdgcn_mfma_f32_16x16x32_bf16(af, b, acc[ct], 0, 0, 0);
            }
        }
    }

    __syncthreads();
    {
        int rbase = wave * 16 + (lane >> 4) * 4;
        #pragma unroll
        for (int r = 0; r < 4; ++r)
            #pragma unroll
            for (int ct = 0; ct < 8; ++ct)
                sC[(rbase + r) * SC_STRIDE + ct * 16 + lrow] = acc[ct][r];
    }
    __syncthreads();

    for (int it = 0; it < 8; ++it) {
        int idx = tid + it * 256;
        int row = idx >> 5;
        int c4  = (idx & 31) << 2;
        int grow = node0 + row;
        if (grow < N) {
            const float* sp = sC + row * SC_STRIDE + c4;
            float4 rv = *(const float4*)(h + (size_t)grow * DIM + c4);
            float4 bv = *(const float4*)(bh + c4);
            bf16x4 pv = *(const bf16x4*)(PH + (size_t)grow * DIM + c4);
            float4 ov;
            ov.x = rv.x + bv.x + (float)pv[0] + sp[0];
            ov.y = rv.y + bv.y + (float)pv[1] + sp[1];
            ov.z = rv.z + bv.z + (float)pv[2] + sp[2];
            ov.w = rv.w + bv.w + (float)pv[3] + sp[3];
            *(float4*)(out + (size_t)grow * DIM + c4) = ov;
        }
    }
}

// ---------------------------------------------------------------------------
// ws layout (~145.4 MB; 153.6 MB proven):
//   P: 4*NB bf16  aggD: NB bf16  offs: 2N int  partials: 256 int
//   recs: (EA+ED) int4  Wt: 10*16384 bf16
// d_out timeline: h_bf (bf16) -> aggA (f32, gather3) -> out (update2).
// ---------------------------------------------------------------------------
static inline size_t align16(size_t x) { return (x + 15) & ~(size_t)15; }

extern "C" void kernel_launch(void* const* d_in, const int* in_sizes, int n_in,
                              void* d_out, int out_size, void* d_ws, size_t ws_size,
                              hipStream_t stream)
{
    const float* h     = (const float*)d_in[0];
    const int*   a_idx = (const int*)d_in[1];
    const float* a_val = (const float*)d_in[2];
    const int*   d_idx = (const int*)d_in[3];
    const float* d_val = (const float*)d_in[4];
    const float* W_a   = (const float*)d_in[5];
    const float* b_a   = (const float*)d_in[6];
    const float* W_d   = (const float*)d_in[7];
    const float* b_d   = (const float*)d_in[8];
    const float* W_h   = (const float*)d_in[9];
    const float* b_h   = (const float*)d_in[10];
    float* out = (float*)d_out;

    const int N  = in_sizes[0] / DIM;   // 100000
    const int EA = in_sizes[2];         // 500000
    const int ED = in_sizes[4];         // 500000
    const size_t NB = (size_t)N * DIM;
    const int twoN = 2 * N;
    const int NBLK = (twoN + SCAN_CHUNK - 1) / SCAN_CHUNK;  // 196 <= 256

    size_t off = 0;
    __bf16* P    = (__bf16*)((char*)d_ws + off); off = align16(off + 4 * NB * sizeof(__bf16));
    __bf16* aggD = (__bf16*)((char*)d_ws + off); off = align16(off + NB * sizeof(__bf16));
    int* offs     = (int*)((char*)d_ws + off);  off = align16(off + (size_t)twoN * sizeof(int));
    int* partials = (int*)((char*)d_ws + off);  off = align16(off + 256 * sizeof(int));
    int4* recs    = (int4*)((char*)d_ws + off); off = align16(off + (size_t)(EA + ED) * sizeof(int4));
    __bf16* Wt  = (__bf16*)((char*)d_ws + off); off = align16(off + (size_t)10 * 16384 * sizeof(__bf16));
    if (ws_size < off) return;  // diagnostic guard

    const int NT64 = (N + 63) / 64;        // 1563
    const int GE = (EA + ED + 255) / 256;  // 3907
    const int HB = (int)((NB / 8 + 255) / 256);  // 6250
    const int WB = (10 * 16384 + 255) / 256;     // 640
    const int GN4 = (N + 3) / 4;           // 25000

    __bf16* h_bf = (__bf16*)d_out;         // transient: dead once gather3 writes

    // --- fused prologue: memset, then count ∥ h2bf ∥ prep_w ---
    hipMemsetAsync(offs, 0, (size_t)twoN * sizeof(int), stream);
    count_prep<<<GE + HB + WB, 256, 0, stream>>>(a_idx, d_idx, offs, h, h_bf,
                                                 W_a, W_d, W_h, Wt,
                                                 EA, ED, N, GE, HB);

    // --- scan ---
    scan_s1<<<NBLK, 256, 0, stream>>>(offs, partials, twoN);
    scan_s2<<<1, 256, 0, stream>>>(partials, NBLK);
    scan_s3<<<NBLK, 256, 0, stream>>>(offs, partials, twoN);

    // --- fused: CSR fill ∥ dihedral proj (Wt slots 0..3 -> P[0..3]) ---
    fill_projD<<<GE + NT64 * 4, 256, 0, stream>>>(a_idx, a_val, d_idx, d_val,
                                                  offs, recs, h_bf, Wt, P,
                                                  EA, ED, N, GE);

    gather4<<<GN4, 256, 0, stream>>>(P, W_d + 512 * DIM, b_d, offs + N, recs, aggD, N);

    // --- angle proj + PH: Wt slots 4..7 -> P[0..2]=Wa, P[3]=h@Wh0 ---
    proj<<<NT64 * 4, 256, 0, stream>>>(h_bf, Wt + (size_t)4 * 16384, P, N);

    // gather3 overwrites d_out (h_bf dead) with aggA f32
    gather3<<<GN4, 256, 0, stream>>>(P, W_a + 384 * DIM, b_a, offs, recs, out, N);

    // --- fused node update: Wh1=slot 8, Wh2=slot 9, + PH epilogue ---
    update2<<<NT64, 256, 0, stream>>>(h, out, aggD, P + 3 * NB, Wt + (size_t)8 * 16384,
                                      b_h, out, N);
}

// Round 14
// 328.577 us; speedup vs baseline: 1.0973x; 1.0973x over previous
//
#include <hip/hip_runtime.h>
#include <hip/hip_bf16.h>

#define DIM 128
#define LDS_STRIDE 136  // bf16 stage stride (272B rows)
#define SC_STRIDE 132   // f32 epilogue stride

typedef __attribute__((ext_vector_type(8))) __bf16 bf16x8;
typedef __attribute__((ext_vector_type(4))) __bf16 bf16x4;
typedef __attribute__((ext_vector_type(4))) float f32x4;

// Wt layout: [0..3]=Wd0..3, [4..6]=Wa0..2, [7]=Wh0, [8]=Wh1, [9]=Wh2

// ---------------------------------------------------------------------------
// prep_w: transpose 10 128x128 W blocks into Wt[t][c][k] bf16 (0.33 MB).
// ---------------------------------------------------------------------------
__global__ __launch_bounds__(256) void prep_w(const float* __restrict__ W_a,
                                              const float* __restrict__ W_d,
                                              const float* __restrict__ W_h,
                                              __bf16* __restrict__ Wt)
{
    int idx = blockIdx.x * 256 + threadIdx.x;
    if (idx >= 10 * 16384) return;
    int t   = idx >> 14;
    int rem = idx & 16383;
    int c   = rem >> 7;
    int k   = rem & 127;
    const float* src;
    if (t < 4)      src = W_d + (size_t)t * 16384;
    else if (t < 7) src = W_a + (size_t)(t - 4) * 16384;
    else            src = W_h + (size_t)(t - 7) * 16384;
    Wt[(size_t)t * 16384 + c * 128 + k] = (__bf16)src[k * 128 + c];
}

// ---------------------------------------------------------------------------
// count_h2bf: per-thread fused. Each thread fires <=1 CSR-count atomic
// (no return use -> fire-and-forget, no wait) then does its h->bf16 chunk.
// ---------------------------------------------------------------------------
__global__ __launch_bounds__(256) void count_h2bf(const int* __restrict__ a_idx,
                                                  const int* __restrict__ d_idx,
                                                  int* __restrict__ offs,
                                                  const float* __restrict__ h,
                                                  __bf16* __restrict__ hb,
                                                  int EA, int ED, int N)
{
    const int gt = blockIdx.x * 256 + threadIdx.x;
    if (gt < EA) {
        atomicAdd(&offs[a_idx[3 * (size_t)gt + 1]], 1);
    } else if (gt < EA + ED) {
        int k = gt - EA;
        atomicAdd(&offs[N + d_idx[4 * (size_t)k + 1]], 1);
    }
    int i = gt * 8;
    if (i < N * DIM) {
        float4 v0 = *(const float4*)(h + i);
        float4 v1 = *(const float4*)(h + i + 4);
        bf16x8 o;
        o[0] = (__bf16)v0.x; o[1] = (__bf16)v0.y; o[2] = (__bf16)v0.z; o[3] = (__bf16)v0.w;
        o[4] = (__bf16)v1.x; o[5] = (__bf16)v1.y; o[6] = (__bf16)v1.z; o[7] = (__bf16)v1.w;
        *(bf16x8*)(hb + i) = o;
    }
}

__device__ __forceinline__ void stage_wt(const __bf16* __restrict__ Wtj,
                                         __bf16 (*sB)[LDS_STRIDE], int tid)
{
    for (int it = 0; it < 8; ++it) {
        int idx = tid + it * 256;
        int c  = idx >> 4;
        int k8 = (idx & 15) << 3;
        *(bf16x8*)&sB[c][k8] = *(const bf16x8*)(Wtj + c * 128 + k8);
    }
}

__device__ __forceinline__ void load_afrag_f32(const float* __restrict__ src,
                                               int row, int lk, int N, bf16x8 afrag[4])
{
    const float* rp = src + (size_t)row * DIM;
    #pragma unroll
    for (int ks = 0; ks < 4; ++ks) {
        float4 v0 = make_float4(0.f, 0.f, 0.f, 0.f), v1 = v0;
        if (row < N) {
            v0 = *(const float4*)(rp + ks * 32 + lk);
            v1 = *(const float4*)(rp + ks * 32 + lk + 4);
        }
        bf16x8 a;
        a[0] = (__bf16)v0.x; a[1] = (__bf16)v0.y; a[2] = (__bf16)v0.z; a[3] = (__bf16)v0.w;
        a[4] = (__bf16)v1.x; a[5] = (__bf16)v1.y; a[6] = (__bf16)v1.z; a[7] = (__bf16)v1.w;
        afrag[ks] = a;
    }
}

__device__ __forceinline__ void load_afrag_bf16(const __bf16* __restrict__ src,
                                                int row, int lk, int N, bf16x8 afrag[4])
{
    const __bf16* rp = src + (size_t)row * DIM;
    #pragma unroll
    for (int ks = 0; ks < 4; ++ks) {
        bf16x8 a = {};
        if (row < N) a = *(const bf16x8*)(rp + ks * 32 + lk);
        afrag[ks] = a;
    }
}

// shared proj body: one (64-row tile, j) pair; bf16 A-loads; LDS epilogue
__device__ __forceinline__ void proj_body(const __bf16* __restrict__ src,
                                          const __bf16* __restrict__ Wtj,
                                          __bf16* __restrict__ dj,
                                          __bf16 (*sB)[LDS_STRIDE],
                                          int node0, int tid, int N)
{
    float* sC = reinterpret_cast<float*>(sB);
    const int wave = tid >> 6, lane = tid & 63;
    const int lrow = lane & 15;
    const int lk   = (lane >> 4) * 8;
    const int arow = node0 + wave * 16 + lrow;

    stage_wt(Wtj, sB, tid);
    bf16x8 afrag[4];
    load_afrag_bf16(src, arow, lk, N, afrag);
    __syncthreads();

    f32x4 acc[8];
    #pragma unroll
    for (int ct = 0; ct < 8; ++ct) acc[ct] = (f32x4){0.f, 0.f, 0.f, 0.f};

    #pragma unroll
    for (int ks = 0; ks < 4; ++ks) {
        int k0 = ks * 32 + lk;
        #pragma unroll
        for (int ct = 0; ct < 8; ++ct) {
            bf16x8 b = *(const bf16x8*)&sB[ct * 16 + lrow][k0];
            acc[ct] = __builtin_amdgcn_mfma_f32_16x16x32_bf16(afrag[ks], b, acc[ct], 0, 0, 0);
        }
    }

    __syncthreads();
    {
        int rbase = wave * 16 + (lane >> 4) * 4;
        #pragma unroll
        for (int r = 0; r < 4; ++r)
            #pragma unroll
            for (int ct = 0; ct < 8; ++ct)
                sC[(rbase + r) * SC_STRIDE + ct * 16 + lrow] = acc[ct][r];
    }
    __syncthreads();

    for (int it = 0; it < 8; ++it) {
        int idx = tid + it * 256;
        int row = idx >> 5;
        int c4  = (idx & 31) << 2;
        int grow = node0 + row;
        if (grow < N) {
            const float* sp = sC + row * SC_STRIDE + c4;
            bf16x4 o;
            o[0] = (__bf16)sp[0]; o[1] = (__bf16)sp[1];
            o[2] = (__bf16)sp[2]; o[3] = (__bf16)sp[3];
            *(bf16x4*)(dj + (size_t)grow * DIM + c4) = o;
        }
    }
}

// ---------------------------------------------------------------------------
// projD_fill: dihedral proj with EMBEDDED per-thread CSR fill (<=1 edge per
// thread). Every block does both roles -> no LDS-reservation occupancy split.
// The fill atomic+store latency hides under stage_wt/afrag issue + MFMA.
// Kernel boundary guarantees all fill done before gather4.
// ---------------------------------------------------------------------------
__global__ __launch_bounds__(256, 4) void projD_fill(const int* __restrict__ a_idx,
                                                     const float* __restrict__ a_val,
                                                     const int* __restrict__ d_idx,
                                                     const float* __restrict__ d_val,
                                                     int* __restrict__ offs,
                                                     int4* __restrict__ recs,
                                                     const __bf16* __restrict__ hb,
                                                     const __bf16* __restrict__ Wt,
                                                     __bf16* __restrict__ P,
                                                     int EA, int ED, int N)
{
    __shared__ __bf16 sB[128][LDS_STRIDE];
    const int tid = threadIdx.x;
    const int pb = blockIdx.x;

    // --- embedded fill: <=1 edge/thread ---
    int e = pb * 256 + tid;
    if (e < EA) {
        int i0 = a_idx[3 * (size_t)e + 0];
        int i1 = a_idx[3 * (size_t)e + 1];
        int i2 = a_idx[3 * (size_t)e + 2];
        int slot = atomicAdd(&offs[i1], 1);
        recs[slot] = make_int4(i0 * 256, i2 * 256, __float_as_int(a_val[e]), 0);
    } else if (e < EA + ED) {
        int k = e - EA;
        int i0 = d_idx[4 * (size_t)k + 0];
        int i1 = d_idx[4 * (size_t)k + 1];
        int i2 = d_idx[4 * (size_t)k + 2];
        int i3 = d_idx[4 * (size_t)k + 3];
        int slot = atomicAdd(&offs[N + i1], 1);
        recs[slot] = make_int4(i0 * 256, i2 * 256, i3 * 256, __float_as_int(d_val[k]));
    }

    // --- proj role (every block) ---
    int tile = pb >> 2, j = pb & 3;   // consecutive blocks share h tile (L2)
    proj_body(hb, Wt + (size_t)j * 16384, P + (size_t)j * N * DIM,
              sB, tile * 64, tid, N);
}

// standalone proj for the angle pass (Wt slots 4..7 -> P[0..2]=Wa, P[3]=Wh0)
__global__ __launch_bounds__(256, 4) void proj(const __bf16* __restrict__ src,
                                               const __bf16* __restrict__ Wt,
                                               __bf16* __restrict__ dst,
                                               int N)
{
    __shared__ __bf16 sB[128][LDS_STRIDE];
    const int pb = blockIdx.x;
    const int tile = pb >> 2, j = pb & 3;
    proj_body(src, Wt + (size_t)j * 16384, dst + (size_t)j * N * DIM,
              sB, tile * 64, threadIdx.x, N);
}

#define SCAN_CHUNK 1024

__global__ __launch_bounds__(256) void scan_s1(int* __restrict__ data,
                                               int* __restrict__ partials, int n)
{
    __shared__ int lds[256];
    const int t = threadIdx.x;
    const int base = blockIdx.x * SCAN_CHUNK + t * 4;
    int v[4];
    #pragma unroll
    for (int i = 0; i < 4; ++i) v[i] = (base + i < n) ? data[base + i] : 0;
    int tsum = v[0] + v[1] + v[2] + v[3];
    lds[t] = tsum; __syncthreads();
    for (int off = 1; off < 256; off <<= 1) {
        int x = (t >= off) ? lds[t - off] : 0;
        __syncthreads();
        lds[t] += x;
        __syncthreads();
    }
    if (t == 255) partials[blockIdx.x] = lds[255];
    int run = lds[t] - tsum;
    #pragma unroll
    for (int i = 0; i < 4; ++i) {
        int nv = run; run += v[i];
        if (base + i < n) data[base + i] = nv;
    }
}

__global__ __launch_bounds__(256) void scan_s2(int* __restrict__ partials, int nb)
{
    __shared__ int lds[256];
    const int t = threadIdx.x;
    int v = (t < nb) ? partials[t] : 0;
    lds[t] = v; __syncthreads();
    for (int off = 1; off < 256; off <<= 1) {
        int x = (t >= off) ? lds[t - off] : 0;
        __syncthreads();
        lds[t] += x;
        __syncthreads();
    }
    if (t < nb) partials[t] = lds[t] - v;
}

__global__ __launch_bounds__(256) void scan_s3(int* __restrict__ data,
                                               const int* __restrict__ partials, int n)
{
    const int add = partials[blockIdx.x];
    const int base = blockIdx.x * SCAN_CHUNK + threadIdx.x * 4;
    #pragma unroll
    for (int i = 0; i < 4; ++i)
        if (base + i < n) data[base + i] += add;
}

__device__ __forceinline__ float silu(float x) { return x / (1.f + __expf(-x)); }

// ---------------------------------------------------------------------------
// gather3: half-wave-per-edge (proven). agg_a f32 -> d_out.
// ---------------------------------------------------------------------------
__global__ __launch_bounds__(256) void gather3(const __bf16* __restrict__ P,
                                               const float* __restrict__ wlast,
                                               const float* __restrict__ bias,
                                               const int* __restrict__ offs,
                                               const int4* __restrict__ recs,
                                               float* __restrict__ aggf, int N)
{
    const int tid = threadIdx.x;
    const int n = blockIdx.x * 4 + (tid >> 6);
    if (n >= N) return;
    const int lane = tid & 63;
    const int half = lane >> 5;
    const int gl = lane & 31;
    const int f  = gl * 4;
    const int fb = gl * 8;
    const size_t NBb = (size_t)N * DIM * 2;
    const char* P0b = (const char*)P;
    const char* P1b = P0b + NBb;
    const char* P2b = P0b + 2 * NBb;
    int start = (n == 0) ? 0 : offs[n - 1];
    int end = offs[n];

    float wl[4], base[4];
    {
        const float* wp = wlast + f;
        const float* bp = bias + f;
        bf16x4 p1 = *(const bf16x4*)(P1b + (size_t)n * 256 + fb);
        #pragma unroll
        for (int c = 0; c < 4; ++c) { wl[c] = wp[c]; base[c] = (float)p1[c] + bp[c]; }
    }
    float a[4] = {0.f, 0.f, 0.f, 0.f};

    const int cnt = end - start;
    const int npair = cnt >> 1;
    int s = start;
    for (int p = 0; p < npair; ++p, s += 2) {
        int4 r = recs[s + half];
        bf16x4 q0 = *(const bf16x4*)(P0b + r.x + fb);
        bf16x4 q2 = *(const bf16x4*)(P2b + r.y + fb);
        float v = __int_as_float(r.z);
        #pragma unroll
        for (int c = 0; c < 4; ++c)
            a[c] += silu((float)q0[c] + (float)q2[c] + v * wl[c] + base[c]);
    }
    if (cnt & 1) {
        int4 r = recs[end - 1];
        bf16x4 q0 = *(const bf16x4*)(P0b + r.x + fb);
        bf16x4 q2 = *(const bf16x4*)(P2b + r.y + fb);
        float v = __int_as_float(r.z);
        if (half == 0) {
            #pragma unroll
            for (int c = 0; c < 4; ++c)
                a[c] += silu((float)q0[c] + (float)q2[c] + v * wl[c] + base[c]);
        }
    }
    #pragma unroll
    for (int c = 0; c < 4; ++c) a[c] += __shfl_xor(a[c], 32, 64);
    if (half == 0) {
        f32x4 o;
        #pragma unroll
        for (int c = 0; c < 4; ++c) o[c] = a[c];
        *(f32x4*)(aggf + (size_t)n * DIM + f) = o;
    }
}

__global__ __launch_bounds__(256) void gather4(const __bf16* __restrict__ P,
                                               const float* __restrict__ wlast,
                                               const float* __restrict__ bias,
                                               const int* __restrict__ offs_d,
                                               const int4* __restrict__ recs,
                                               __bf16* __restrict__ agg, int N)
{
    const int tid = threadIdx.x;
    const int n = blockIdx.x * 4 + (tid >> 6);
    if (n >= N) return;
    const int lane = tid & 63;
    const int half = lane >> 5;
    const int gl = lane & 31;
    const int f  = gl * 4;
    const int fb = gl * 8;
    const size_t NBb = (size_t)N * DIM * 2;
    const char* P0b = (const char*)P;
    const char* P1b = P0b + NBb;
    const char* P2b = P0b + 2 * NBb;
    const char* P3b = P0b + 3 * NBb;
    int start = offs_d[n - 1];  // n==0 -> offs[N-1] == EA == dihedral base
    int end = offs_d[n];

    float wl[4], base[4];
    {
        const float* wp = wlast + f;
        const float* bp = bias + f;
        bf16x4 p1 = *(const bf16x4*)(P1b + (size_t)n * 256 + fb);
        #pragma unroll
        for (int c = 0; c < 4; ++c) { wl[c] = wp[c]; base[c] = (float)p1[c] + bp[c]; }
    }
    float a[4] = {0.f, 0.f, 0.f, 0.f};

    const int cnt = end - start;
    const int npair = cnt >> 1;
    int s = start;
    for (int p = 0; p < npair; ++p, s += 2) {
        int4 r = recs[s + half];
        bf16x4 q0 = *(const bf16x4*)(P0b + r.x + fb);
        bf16x4 q2 = *(const bf16x4*)(P2b + r.y + fb);
        bf16x4 q3 = *(const bf16x4*)(P3b + r.z + fb);
        float v = __int_as_float(r.w);
        #pragma unroll
        for (int c = 0; c < 4; ++c)
            a[c] += silu((float)q0[c] + (float)q2[c] + (float)q3[c] + v * wl[c] + base[c]);
    }
    if (cnt & 1) {
        int4 r = recs[end - 1];
        bf16x4 q0 = *(const bf16x4*)(P0b + r.x + fb);
        bf16x4 q2 = *(const bf16x4*)(P2b + r.y + fb);
        bf16x4 q3 = *(const bf16x4*)(P3b + r.z + fb);
        float v = __int_as_float(r.w);
        if (half == 0) {
            #pragma unroll
            for (int c = 0; c < 4; ++c)
                a[c] += silu((float)q0[c] + (float)q2[c] + (float)q3[c] + v * wl[c] + base[c]);
        }
    }
    #pragma unroll
    for (int c = 0; c < 4; ++c) a[c] += __shfl_xor(a[c], 32, 64);
    if (half == 0) {
        bf16x4 o;
        #pragma unroll
        for (int c = 0; c < 4; ++c) o[c] = (__bf16)a[c];
        *(bf16x4*)(agg + (size_t)n * DIM + f) = o;
    }
}

// ---------------------------------------------------------------------------
// update2: out = h + bh + PH + aggA@Wt[0] + aggD@Wt[1]   (2 MFMA stages)
// PH = h@Wh0 from the angle proj pass (P[3]). aggA lives IN d_out.
// ---------------------------------------------------------------------------
__global__ __launch_bounds__(256, 4) void update2(const float* __restrict__ h,
                                                  const float* __restrict__ aggA,
                                                  const __bf16* __restrict__ aggD,
                                                  const __bf16* __restrict__ PH,
                                                  const __bf16* __restrict__ Wt,
                                                  const float* __restrict__ bh,
                                                  float* __restrict__ out, int N)
{
    __shared__ __bf16 sB[128][LDS_STRIDE];
    float* sC = reinterpret_cast<float*>(sB);
    const int tid = threadIdx.x;
    const int node0 = blockIdx.x * 64;
    const int wave = tid >> 6, lane = tid & 63;
    const int lrow = lane & 15;
    const int lk   = (lane >> 4) * 8;
    const int arow = node0 + wave * 16 + lrow;

    bf16x8 aA[4], aD[4];
    load_afrag_f32(aggA, arow, lk, N, aA);
    load_afrag_bf16(aggD, arow, lk, N, aD);

    f32x4 acc[8];
    #pragma unroll
    for (int ct = 0; ct < 8; ++ct) acc[ct] = (f32x4){0.f, 0.f, 0.f, 0.f};

    #pragma unroll
    for (int s = 0; s < 2; ++s) {
        __syncthreads();
        stage_wt(Wt + (size_t)s * 16384, sB, tid);
        __syncthreads();

        #pragma unroll
        for (int ks = 0; ks < 4; ++ks) {
            int k0 = ks * 32 + lk;
            #pragma unroll
            for (int ct = 0; ct < 8; ++ct) {
                bf16x8 b = *(const bf16x8*)&sB[ct * 16 + lrow][k0];
                bf16x8 af = (s == 0) ? aA[ks] : aD[ks];
                acc[ct] = __builtin_amdgcn_mfma_f32_16x16x32_bf16(af, b, acc[ct], 0, 0, 0);
            }
        }
    }

    __syncthreads();
    {
        int rbase = wave * 16 + (lane >> 4) * 4;
        #pragma unroll
        for (int r = 0; r < 4; ++r)
            #pragma unroll
            for (int ct = 0; ct < 8; ++ct)
                sC[(rbase + r) * SC_STRIDE + ct * 16 + lrow] = acc[ct][r];
    }
    __syncthreads();

    for (int it = 0; it < 8; ++it) {
        int idx = tid + it * 256;
        int row = idx >> 5;
        int c4  = (idx & 31) << 2;
        int grow = node0 + row;
        if (grow < N) {
            const float* sp = sC + row * SC_STRIDE + c4;
            float4 rv = *(const float4*)(h + (size_t)grow * DIM + c4);
            float4 bv = *(const float4*)(bh + c4);
            bf16x4 pv = *(const bf16x4*)(PH + (size_t)grow * DIM + c4);
            float4 ov;
            ov.x = rv.x + bv.x + (float)pv[0] + sp[0];
            ov.y = rv.y + bv.y + (float)pv[1] + sp[1];
            ov.z = rv.z + bv.z + (float)pv[2] + sp[2];
            ov.w = rv.w + bv.w + (float)pv[3] + sp[3];
            *(float4*)(out + (size_t)grow * DIM + c4) = ov;
        }
    }
}

// ---------------------------------------------------------------------------
// ws layout (~145.4 MB; 153.6 MB proven):
//   P: 4*NB bf16  aggD: NB bf16  offs: 2N int  partials: 256 int
//   recs: (EA+ED) int4  Wt: 10*16384 bf16
// d_out timeline: h_bf (bf16) -> aggA (f32, gather3) -> out (update2).
// ---------------------------------------------------------------------------
static inline size_t align16(size_t x) { return (x + 15) & ~(size_t)15; }

extern "C" void kernel_launch(void* const* d_in, const int* in_sizes, int n_in,
                              void* d_out, int out_size, void* d_ws, size_t ws_size,
                              hipStream_t stream)
{
    const float* h     = (const float*)d_in[0];
    const int*   a_idx = (const int*)d_in[1];
    const float* a_val = (const float*)d_in[2];
    const int*   d_idx = (const int*)d_in[3];
    const float* d_val = (const float*)d_in[4];
    const float* W_a   = (const float*)d_in[5];
    const float* b_a   = (const float*)d_in[6];
    const float* W_d   = (const float*)d_in[7];
    const float* b_d   = (const float*)d_in[8];
    const float* W_h   = (const float*)d_in[9];
    const float* b_h   = (const float*)d_in[10];
    float* out = (float*)d_out;

    const int N  = in_sizes[0] / DIM;   // 100000
    const int EA = in_sizes[2];         // 500000
    const int ED = in_sizes[4];         // 500000
    const size_t NB = (size_t)N * DIM;
    const int twoN = 2 * N;
    const int NBLK = (twoN + SCAN_CHUNK - 1) / SCAN_CHUNK;  // 196 <= 256

    size_t off = 0;
    __bf16* P    = (__bf16*)((char*)d_ws + off); off = align16(off + 4 * NB * sizeof(__bf16));
    __bf16* aggD = (__bf16*)((char*)d_ws + off); off = align16(off + NB * sizeof(__bf16));
    int* offs     = (int*)((char*)d_ws + off);  off = align16(off + (size_t)twoN * sizeof(int));
    int* partials = (int*)((char*)d_ws + off);  off = align16(off + 256 * sizeof(int));
    int4* recs    = (int4*)((char*)d_ws + off); off = align16(off + (size_t)(EA + ED) * sizeof(int4));
    __bf16* Wt  = (__bf16*)((char*)d_ws + off); off = align16(off + (size_t)10 * 16384 * sizeof(__bf16));
    if (ws_size < off) return;  // diagnostic guard

    const int NT64 = (N + 63) / 64;              // 1563
    const int HB = (int)((NB / 8 + 255) / 256);  // 6250 (covers EA+ED=1M threads too)
    const int GN4 = (N + 3) / 4;                 // 25000

    __bf16* h_bf = (__bf16*)d_out;               // transient: dead once gather3 writes

    prep_w<<<(10 * 16384 + 255) / 256, 256, 0, stream>>>(W_a, W_d, W_h, Wt);
    hipMemsetAsync(offs, 0, (size_t)twoN * sizeof(int), stream);

    // count (fire-and-forget atomics) embedded in h2bf
    count_h2bf<<<HB, 256, 0, stream>>>(a_idx, d_idx, offs, h, h_bf, EA, ED, N);

    scan_s1<<<NBLK, 256, 0, stream>>>(offs, partials, twoN);
    scan_s2<<<1, 256, 0, stream>>>(partials, NBLK);
    scan_s3<<<NBLK, 256, 0, stream>>>(offs, partials, twoN);

    // dihedral proj with embedded CSR fill (Wt slots 0..3 -> P[0..3])
    projD_fill<<<NT64 * 4, 256, 0, stream>>>(a_idx, a_val, d_idx, d_val,
                                             offs, recs, h_bf, Wt, P, EA, ED, N);

    gather4<<<GN4, 256, 0, stream>>>(P, W_d + 512 * DIM, b_d, offs + N, recs, aggD, N);

    // angle proj + PH: Wt slots 4..7 -> P[0..2]=Wa, P[3]=h@Wh0
    proj<<<NT64 * 4, 256, 0, stream>>>(h_bf, Wt + (size_t)4 * 16384, P, N);

    // gather3 overwrites d_out (h_bf dead) with aggA f32
    gather3<<<GN4, 256, 0, stream>>>(P, W_a + 384 * DIM, b_a, offs, recs, out, N);

    // fused node update: Wh1=slot 8, Wh2=slot 9, + PH epilogue
    update2<<<NT64, 256, 0, stream>>>(h, out, aggD, P + 3 * NB, Wt + (size_t)8 * 16384,
                                      b_h, out, N);
}

// Round 15
// 318.846 us; speedup vs baseline: 1.1308x; 1.0305x over previous
//
#include <hip/hip_runtime.h>
#include <hip/hip_bf16.h>

#define DIM 128
#define LDS_STRIDE 136  // bf16 stage stride (272B rows)
#define SC_STRIDE 132   // f32 epilogue stride

typedef __attribute__((ext_vector_type(8))) __bf16 bf16x8;
typedef __attribute__((ext_vector_type(4))) __bf16 bf16x4;
typedef __attribute__((ext_vector_type(4))) float f32x4;

// Wt layout: [0..3]=Wd0..3, [4..6]=Wa0..2, [7]=Wh0, [8]=Wh1, [9]=Wh2

// ---------------------------------------------------------------------------
// prep_w: transpose 10 128x128 W blocks into Wt[t][c][k] bf16 (0.33 MB).
// ---------------------------------------------------------------------------
__global__ __launch_bounds__(256) void prep_w(const float* __restrict__ W_a,
                                              const float* __restrict__ W_d,
                                              const float* __restrict__ W_h,
                                              __bf16* __restrict__ Wt)
{
    int idx = blockIdx.x * 256 + threadIdx.x;
    if (idx >= 10 * 16384) return;
    int t   = idx >> 14;
    int rem = idx & 16383;
    int c   = rem >> 7;
    int k   = rem & 127;
    const float* src;
    if (t < 4)      src = W_d + (size_t)t * 16384;
    else if (t < 7) src = W_a + (size_t)(t - 4) * 16384;
    else            src = W_h + (size_t)(t - 7) * 16384;
    Wt[(size_t)t * 16384 + c * 128 + k] = (__bf16)src[k * 128 + c];
}

// ---------------------------------------------------------------------------
// count_h2bf: <=1 fire-and-forget count atomic per thread + h->bf16 chunk.
// ---------------------------------------------------------------------------
__global__ __launch_bounds__(256) void count_h2bf(const int* __restrict__ a_idx,
                                                  const int* __restrict__ d_idx,
                                                  int* __restrict__ offs,
                                                  const float* __restrict__ h,
                                                  __bf16* __restrict__ hb,
                                                  int EA, int ED, int N)
{
    const int gt = blockIdx.x * 256 + threadIdx.x;
    if (gt < EA) {
        atomicAdd(&offs[a_idx[3 * (size_t)gt + 1]], 1);
    } else if (gt < EA + ED) {
        int k = gt - EA;
        atomicAdd(&offs[N + d_idx[4 * (size_t)k + 1]], 1);
    }
    int i = gt * 8;
    if (i < N * DIM) {
        float4 v0 = *(const float4*)(h + i);
        float4 v1 = *(const float4*)(h + i + 4);
        bf16x8 o;
        o[0] = (__bf16)v0.x; o[1] = (__bf16)v0.y; o[2] = (__bf16)v0.z; o[3] = (__bf16)v0.w;
        o[4] = (__bf16)v1.x; o[5] = (__bf16)v1.y; o[6] = (__bf16)v1.z; o[7] = (__bf16)v1.w;
        *(bf16x8*)(hb + i) = o;
    }
}

__device__ __forceinline__ void stage_wt(const __bf16* __restrict__ Wtj,
                                         __bf16 (*sB)[LDS_STRIDE], int tid)
{
    for (int it = 0; it < 8; ++it) {
        int idx = tid + it * 256;
        int c  = idx >> 4;
        int k8 = (idx & 15) << 3;
        *(bf16x8*)&sB[c][k8] = *(const bf16x8*)(Wtj + c * 128 + k8);
    }
}

__device__ __forceinline__ void load_afrag_bf16(const __bf16* __restrict__ src,
                                                int row, int stride, int lk, int N,
                                                bf16x8 afrag[4])
{
    const __bf16* rp = src + (size_t)row * stride;
    #pragma unroll
    for (int ks = 0; ks < 4; ++ks) {
        bf16x8 a = {};
        if (row < N) a = *(const bf16x8*)(rp + ks * 32 + lk);
        afrag[ks] = a;
    }
}

// shared proj body: one (64-row tile, j) pair; bf16 A-loads; LDS epilogue
__device__ __forceinline__ void proj_body(const __bf16* __restrict__ src,
                                          const __bf16* __restrict__ Wtj,
                                          __bf16* __restrict__ dj,
                                          __bf16 (*sB)[LDS_STRIDE],
                                          int node0, int tid, int N)
{
    float* sC = reinterpret_cast<float*>(sB);
    const int wave = tid >> 6, lane = tid & 63;
    const int lrow = lane & 15;
    const int lk   = (lane >> 4) * 8;
    const int arow = node0 + wave * 16 + lrow;

    stage_wt(Wtj, sB, tid);
    bf16x8 afrag[4];
    load_afrag_bf16(src, arow, DIM, lk, N, afrag);
    __syncthreads();

    f32x4 acc[8];
    #pragma unroll
    for (int ct = 0; ct < 8; ++ct) acc[ct] = (f32x4){0.f, 0.f, 0.f, 0.f};

    #pragma unroll
    for (int ks = 0; ks < 4; ++ks) {
        int k0 = ks * 32 + lk;
        #pragma unroll
        for (int ct = 0; ct < 8; ++ct) {
            bf16x8 b = *(const bf16x8*)&sB[ct * 16 + lrow][k0];
            acc[ct] = __builtin_amdgcn_mfma_f32_16x16x32_bf16(afrag[ks], b, acc[ct], 0, 0, 0);
        }
    }

    __syncthreads();
    {
        int rbase = wave * 16 + (lane >> 4) * 4;
        #pragma unroll
        for (int r = 0; r < 4; ++r)
            #pragma unroll
            for (int ct = 0; ct < 8; ++ct)
                sC[(rbase + r) * SC_STRIDE + ct * 16 + lrow] = acc[ct][r];
    }
    __syncthreads();

    for (int it = 0; it < 8; ++it) {
        int idx = tid + it * 256;
        int row = idx >> 5;
        int c4  = (idx & 31) << 2;
        int grow = node0 + row;
        if (grow < N) {
            const float* sp = sC + row * SC_STRIDE + c4;
            bf16x4 o;
            o[0] = (__bf16)sp[0]; o[1] = (__bf16)sp[1];
            o[2] = (__bf16)sp[2]; o[3] = (__bf16)sp[3];
            *(bf16x4*)(dj + (size_t)grow * DIM + c4) = o;
        }
    }
}

// ---------------------------------------------------------------------------
// projD_fill: dihedral proj with EMBEDDED per-thread CSR fill (<=1 edge).
// ---------------------------------------------------------------------------
__global__ __launch_bounds__(256, 4) void projD_fill(const int* __restrict__ a_idx,
                                                     const float* __restrict__ a_val,
                                                     const int* __restrict__ d_idx,
                                                     const float* __restrict__ d_val,
                                                     int* __restrict__ offs,
                                                     int4* __restrict__ recs,
                                                     const __bf16* __restrict__ hb,
                                                     const __bf16* __restrict__ Wt,
                                                     __bf16* __restrict__ P,
                                                     int EA, int ED, int N)
{
    __shared__ __bf16 sB[128][LDS_STRIDE];
    const int tid = threadIdx.x;
    const int pb = blockIdx.x;

    int e = pb * 256 + tid;
    if (e < EA) {
        int i0 = a_idx[3 * (size_t)e + 0];
        int i1 = a_idx[3 * (size_t)e + 1];
        int i2 = a_idx[3 * (size_t)e + 2];
        int slot = atomicAdd(&offs[i1], 1);
        recs[slot] = make_int4(i0 * 256, i2 * 256, __float_as_int(a_val[e]), 0);
    } else if (e < EA + ED) {
        int k = e - EA;
        int i0 = d_idx[4 * (size_t)k + 0];
        int i1 = d_idx[4 * (size_t)k + 1];
        int i2 = d_idx[4 * (size_t)k + 2];
        int i3 = d_idx[4 * (size_t)k + 3];
        int slot = atomicAdd(&offs[N + i1], 1);
        recs[slot] = make_int4(i0 * 256, i2 * 256, i3 * 256, __float_as_int(d_val[k]));
    }

    int tile = pb >> 2, j = pb & 3;
    proj_body(hb, Wt + (size_t)j * 16384, P + (size_t)j * N * DIM,
              sB, tile * 64, tid, N);
}

// standalone proj for the angle pass (Wt slots 4..7 -> P[0..2]=Wa, P[3]=Wh0)
__global__ __launch_bounds__(256, 4) void proj(const __bf16* __restrict__ src,
                                               const __bf16* __restrict__ Wt,
                                               __bf16* __restrict__ dst,
                                               int N)
{
    __shared__ __bf16 sB[128][LDS_STRIDE];
    const int pb = blockIdx.x;
    const int tile = pb >> 2, j = pb & 3;
    proj_body(src, Wt + (size_t)j * 16384, dst + (size_t)j * N * DIM,
              sB, tile * 64, threadIdx.x, N);
}

#define SCAN_CHUNK 1024

__global__ __launch_bounds__(256) void scan_s1(int* __restrict__ data,
                                               int* __restrict__ partials, int n)
{
    __shared__ int lds[256];
    const int t = threadIdx.x;
    const int base = blockIdx.x * SCAN_CHUNK + t * 4;
    int v[4];
    #pragma unroll
    for (int i = 0; i < 4; ++i) v[i] = (base + i < n) ? data[base + i] : 0;
    int tsum = v[0] + v[1] + v[2] + v[3];
    lds[t] = tsum; __syncthreads();
    for (int off = 1; off < 256; off <<= 1) {
        int x = (t >= off) ? lds[t - off] : 0;
        __syncthreads();
        lds[t] += x;
        __syncthreads();
    }
    if (t == 255) partials[blockIdx.x] = lds[255];
    int run = lds[t] - tsum;
    #pragma unroll
    for (int i = 0; i < 4; ++i) {
        int nv = run; run += v[i];
        if (base + i < n) data[base + i] = nv;
    }
}

__global__ __launch_bounds__(256) void scan_s2(int* __restrict__ partials, int nb)
{
    __shared__ int lds[256];
    const int t = threadIdx.x;
    int v = (t < nb) ? partials[t] : 0;
    lds[t] = v; __syncthreads();
    for (int off = 1; off < 256; off <<= 1) {
        int x = (t >= off) ? lds[t - off] : 0;
        __syncthreads();
        lds[t] += x;
        __syncthreads();
    }
    if (t < nb) partials[t] = lds[t] - v;
}

__global__ __launch_bounds__(256) void scan_s3(int* __restrict__ data,
                                               const int* __restrict__ partials, int n)
{
    const int add = partials[blockIdx.x];
    const int base = blockIdx.x * SCAN_CHUNK + threadIdx.x * 4;
    #pragma unroll
    for (int i = 0; i < 4; ++i)
        if (base + i < n) data[base + i] += add;
}

// fast silu: x * v_rcp_f32(1 + exp(-x)). ~1ulp rcp, correct at +/-inf.
__device__ __forceinline__ float silu(float x)
{
    return x * __builtin_amdgcn_rcpf(1.f + __expf(-x));
}

// ---------------------------------------------------------------------------
// gather3: half-wave-per-edge. agg_a -> d_out as bf16, strided 256 elem/row
// (row r occupies first 256B of out-row r's 512B slot -> block-local alias
// in update2, no cross-block race).
// ---------------------------------------------------------------------------
__global__ __launch_bounds__(256) void gather3(const __bf16* __restrict__ P,
                                               const float* __restrict__ wlast,
                                               const float* __restrict__ bias,
                                               const int* __restrict__ offs,
                                               const int4* __restrict__ recs,
                                               __bf16* __restrict__ aggb, int N)
{
    const int tid = threadIdx.x;
    const int n = blockIdx.x * 4 + (tid >> 6);
    if (n >= N) return;
    const int lane = tid & 63;
    const int half = lane >> 5;
    const int gl = lane & 31;
    const int f  = gl * 4;
    const int fb = gl * 8;
    const size_t NBb = (size_t)N * DIM * 2;
    const char* P0b = (const char*)P;
    const char* P1b = P0b + NBb;
    const char* P2b = P0b + 2 * NBb;
    int start = (n == 0) ? 0 : offs[n - 1];
    int end = offs[n];

    float wl[4], base[4];
    {
        const float* wp = wlast + f;
        const float* bp = bias + f;
        bf16x4 p1 = *(const bf16x4*)(P1b + (size_t)n * 256 + fb);
        #pragma unroll
        for (int c = 0; c < 4; ++c) { wl[c] = wp[c]; base[c] = (float)p1[c] + bp[c]; }
    }
    float a[4] = {0.f, 0.f, 0.f, 0.f};

    const int cnt = end - start;
    const int npair = cnt >> 1;
    int s = start;
    for (int p = 0; p < npair; ++p, s += 2) {
        int4 r = recs[s + half];
        bf16x4 q0 = *(const bf16x4*)(P0b + r.x + fb);
        bf16x4 q2 = *(const bf16x4*)(P2b + r.y + fb);
        float v = __int_as_float(r.z);
        #pragma unroll
        for (int c = 0; c < 4; ++c)
            a[c] += silu((float)q0[c] + (float)q2[c] + v * wl[c] + base[c]);
    }
    if (cnt & 1) {
        int4 r = recs[end - 1];
        bf16x4 q0 = *(const bf16x4*)(P0b + r.x + fb);
        bf16x4 q2 = *(const bf16x4*)(P2b + r.y + fb);
        float v = __int_as_float(r.z);
        if (half == 0) {
            #pragma unroll
            for (int c = 0; c < 4; ++c)
                a[c] += silu((float)q0[c] + (float)q2[c] + v * wl[c] + base[c]);
        }
    }
    #pragma unroll
    for (int c = 0; c < 4; ++c) a[c] += __shfl_xor(a[c], 32, 64);
    if (half == 0) {
        bf16x4 o;
        #pragma unroll
        for (int c = 0; c < 4; ++c) o[c] = (__bf16)a[c];
        *(bf16x4*)(aggb + (size_t)n * 256 + f) = o;   // stride 256 elem (512B)
    }
}

__global__ __launch_bounds__(256) void gather4(const __bf16* __restrict__ P,
                                               const float* __restrict__ wlast,
                                               const float* __restrict__ bias,
                                               const int* __restrict__ offs_d,
                                               const int4* __restrict__ recs,
                                               __bf16* __restrict__ agg, int N)
{
    const int tid = threadIdx.x;
    const int n = blockIdx.x * 4 + (tid >> 6);
    if (n >= N) return;
    const int lane = tid & 63;
    const int half = lane >> 5;
    const int gl = lane & 31;
    const int f  = gl * 4;
    const int fb = gl * 8;
    const size_t NBb = (size_t)N * DIM * 2;
    const char* P0b = (const char*)P;
    const char* P1b = P0b + NBb;
    const char* P2b = P0b + 2 * NBb;
    const char* P3b = P0b + 3 * NBb;
    int start = offs_d[n - 1];  // n==0 -> offs[N-1] == EA == dihedral base
    int end = offs_d[n];

    float wl[4], base[4];
    {
        const float* wp = wlast + f;
        const float* bp = bias + f;
        bf16x4 p1 = *(const bf16x4*)(P1b + (size_t)n * 256 + fb);
        #pragma unroll
        for (int c = 0; c < 4; ++c) { wl[c] = wp[c]; base[c] = (float)p1[c] + bp[c]; }
    }
    float a[4] = {0.f, 0.f, 0.f, 0.f};

    const int cnt = end - start;
    const int npair = cnt >> 1;
    int s = start;
    for (int p = 0; p < npair; ++p, s += 2) {
        int4 r = recs[s + half];
        bf16x4 q0 = *(const bf16x4*)(P0b + r.x + fb);
        bf16x4 q2 = *(const bf16x4*)(P2b + r.y + fb);
        bf16x4 q3 = *(const bf16x4*)(P3b + r.z + fb);
        float v = __int_as_float(r.w);
        #pragma unroll
        for (int c = 0; c < 4; ++c)
            a[c] += silu((float)q0[c] + (float)q2[c] + (float)q3[c] + v * wl[c] + base[c]);
    }
    if (cnt & 1) {
        int4 r = recs[end - 1];
        bf16x4 q0 = *(const bf16x4*)(P0b + r.x + fb);
        bf16x4 q2 = *(const bf16x4*)(P2b + r.y + fb);
        bf16x4 q3 = *(const bf16x4*)(P3b + r.z + fb);
        float v = __int_as_float(r.w);
        if (half == 0) {
            #pragma unroll
            for (int c = 0; c < 4; ++c)
                a[c] += silu((float)q0[c] + (float)q2[c] + (float)q3[c] + v * wl[c] + base[c]);
        }
    }
    #pragma unroll
    for (int c = 0; c < 4; ++c) a[c] += __shfl_xor(a[c], 32, 64);
    if (half == 0) {
        bf16x4 o;
        #pragma unroll
        for (int c = 0; c < 4; ++c) o[c] = (__bf16)a[c];
        *(bf16x4*)(agg + (size_t)n * DIM + f) = o;
    }
}

// ---------------------------------------------------------------------------
// update2: out = h + bh + PH + aggA@Wt[0] + aggD@Wt[1]   (2 MFMA stages)
// aggA is bf16 with row-stride 256, living inside d_out's row slots
// (block-local aliasing only). PH = h@Wh0 from angle proj pass (P[3]).
// ---------------------------------------------------------------------------
__global__ __launch_bounds__(256, 4) void update2(const float* __restrict__ h,
                                                  const __bf16* __restrict__ aggA,
                                                  const __bf16* __restrict__ aggD,
                                                  const __bf16* __restrict__ PH,
                                                  const __bf16* __restrict__ Wt,
                                                  const float* __restrict__ bh,
                                                  float* __restrict__ out, int N)
{
    __shared__ __bf16 sB[128][LDS_STRIDE];
    float* sC = reinterpret_cast<float*>(sB);
    const int tid = threadIdx.x;
    const int node0 = blockIdx.x * 64;
    const int wave = tid >> 6, lane = tid & 63;
    const int lrow = lane & 15;
    const int lk   = (lane >> 4) * 8;
    const int arow = node0 + wave * 16 + lrow;

    bf16x8 aA[4], aD[4];
    load_afrag_bf16(aggA, arow, 256, lk, N, aA);   // strided aggA in d_out
    load_afrag_bf16(aggD, arow, DIM, lk, N, aD);

    f32x4 acc[8];
    #pragma unroll
    for (int ct = 0; ct < 8; ++ct) acc[ct] = (f32x4){0.f, 0.f, 0.f, 0.f};

    #pragma unroll
    for (int s = 0; s < 2; ++s) {
        __syncthreads();
        stage_wt(Wt + (size_t)s * 16384, sB, tid);
        __syncthreads();

        #pragma unroll
        for (int ks = 0; ks < 4; ++ks) {
            int k0 = ks * 32 + lk;
            #pragma unroll
            for (int ct = 0; ct < 8; ++ct) {
                bf16x8 b = *(const bf16x8*)&sB[ct * 16 + lrow][k0];
                bf16x8 af = (s == 0) ? aA[ks] : aD[ks];
                acc[ct] = __builtin_amdgcn_mfma_f32_16x16x32_bf16(af, b, acc[ct], 0, 0, 0);
            }
        }
    }

    __syncthreads();
    {
        int rbase = wave * 16 + (lane >> 4) * 4;
        #pragma unroll
        for (int r = 0; r < 4; ++r)
            #pragma unroll
            for (int ct = 0; ct < 8; ++ct)
                sC[(rbase + r) * SC_STRIDE + ct * 16 + lrow] = acc[ct][r];
    }
    __syncthreads();

    for (int it = 0; it < 8; ++it) {
        int idx = tid + it * 256;
        int row = idx >> 5;
        int c4  = (idx & 31) << 2;
        int grow = node0 + row;
        if (grow < N) {
            const float* sp = sC + row * SC_STRIDE + c4;
            float4 rv = *(const float4*)(h + (size_t)grow * DIM + c4);
            float4 bv = *(const float4*)(bh + c4);
            bf16x4 pv = *(const bf16x4*)(PH + (size_t)grow * DIM + c4);
            float4 ov;
            ov.x = rv.x + bv.x + (float)pv[0] + sp[0];
            ov.y = rv.y + bv.y + (float)pv[1] + sp[1];
            ov.z = rv.z + bv.z + (float)pv[2] + sp[2];
            ov.w = rv.w + bv.w + (float)pv[3] + sp[3];
            *(float4*)(out + (size_t)grow * DIM + c4) = ov;
        }
    }
}

// ---------------------------------------------------------------------------
// ws layout (~145.4 MB; 153.6 MB proven):
//   P: 4*NB bf16  aggD: NB bf16  offs: 2N int  partials: 256 int
//   recs: (EA+ED) int4  Wt: 10*16384 bf16
// d_out timeline: h_bf (bf16, packed) -> aggA (bf16, 512B-strided row slots,
// written by gather3 AFTER projA consumed h_bf) -> out (f32, update2).
// ---------------------------------------------------------------------------
static inline size_t align16(size_t x) { return (x + 15) & ~(size_t)15; }

extern "C" void kernel_launch(void* const* d_in, const int* in_sizes, int n_in,
                              void* d_out, int out_size, void* d_ws, size_t ws_size,
                              hipStream_t stream)
{
    const float* h     = (const float*)d_in[0];
    const int*   a_idx = (const int*)d_in[1];
    const float* a_val = (const float*)d_in[2];
    const int*   d_idx = (const int*)d_in[3];
    const float* d_val = (const float*)d_in[4];
    const float* W_a   = (const float*)d_in[5];
    const float* b_a   = (const float*)d_in[6];
    const float* W_d   = (const float*)d_in[7];
    const float* b_d   = (const float*)d_in[8];
    const float* W_h   = (const float*)d_in[9];
    const float* b_h   = (const float*)d_in[10];
    float* out = (float*)d_out;

    const int N  = in_sizes[0] / DIM;   // 100000
    const int EA = in_sizes[2];         // 500000
    const int ED = in_sizes[4];         // 500000
    const size_t NB = (size_t)N * DIM;
    const int twoN = 2 * N;
    const int NBLK = (twoN + SCAN_CHUNK - 1) / SCAN_CHUNK;  // 196 <= 256

    size_t off = 0;
    __bf16* P    = (__bf16*)((char*)d_ws + off); off = align16(off + 4 * NB * sizeof(__bf16));
    __bf16* aggD = (__bf16*)((char*)d_ws + off); off = align16(off + NB * sizeof(__bf16));
    int* offs     = (int*)((char*)d_ws + off);  off = align16(off + (size_t)twoN * sizeof(int));
    int* partials = (int*)((char*)d_ws + off);  off = align16(off + 256 * sizeof(int));
    int4* recs    = (int4*)((char*)d_ws + off); off = align16(off + (size_t)(EA + ED) * sizeof(int4));
    __bf16* Wt  = (__bf16*)((char*)d_ws + off); off = align16(off + (size_t)10 * 16384 * sizeof(__bf16));
    if (ws_size < off) return;  // diagnostic guard

    const int NT64 = (N + 63) / 64;              // 1563
    const int HB = (int)((NB / 8 + 255) / 256);  // 6250 (covers EA+ED=1M threads too)
    const int GN4 = (N + 3) / 4;                 // 25000

    __bf16* h_bf = (__bf16*)d_out;               // transient, packed N*128 bf16
    __bf16* aggA = (__bf16*)d_out;               // later: 512B-strided rows

    prep_w<<<(10 * 16384 + 255) / 256, 256, 0, stream>>>(W_a, W_d, W_h, Wt);
    hipMemsetAsync(offs, 0, (size_t)twoN * sizeof(int), stream);

    // count (fire-and-forget atomics) embedded in h2bf
    count_h2bf<<<HB, 256, 0, stream>>>(a_idx, d_idx, offs, h, h_bf, EA, ED, N);

    scan_s1<<<NBLK, 256, 0, stream>>>(offs, partials, twoN);
    scan_s2<<<1, 256, 0, stream>>>(partials, NBLK);
    scan_s3<<<NBLK, 256, 0, stream>>>(offs, partials, twoN);

    // dihedral proj with embedded CSR fill (Wt slots 0..3 -> P[0..3])
    projD_fill<<<NT64 * 4, 256, 0, stream>>>(a_idx, a_val, d_idx, d_val,
                                             offs, recs, h_bf, Wt, P, EA, ED, N);

    gather4<<<GN4, 256, 0, stream>>>(P, W_d + 512 * DIM, b_d, offs + N, recs, aggD, N);

    // angle proj + PH: Wt slots 4..7 -> P[0..2]=Wa, P[3]=h@Wh0
    proj<<<NT64 * 4, 256, 0, stream>>>(h_bf, Wt + (size_t)4 * 16384, P, N);

    // gather3 overwrites d_out (h_bf dead) with aggA bf16, 512B-strided rows
    gather3<<<GN4, 256, 0, stream>>>(P, W_a + 384 * DIM, b_a, offs, recs, aggA, N);

    // fused node update: Wh1=slot 8, Wh2=slot 9, + PH epilogue
    update2<<<NT64, 256, 0, stream>>>(h, aggA, aggD, P + 3 * NB, Wt + (size_t)8 * 16384,
                                      b_h, out, N);
}